// Round 10
// baseline (224.552 us; speedup 1.0000x reference)
//
#include <hip/hip_runtime.h>
#include <hip/hip_bf16.h>

typedef __hip_bfloat16 bf16;
typedef float f32x4 __attribute__((ext_vector_type(4)));
typedef short s16x8 __attribute__((ext_vector_type(8)));

// ---------------------------------------------------------------------------
__device__ __forceinline__ void async_load16(const void* g, void* lds) {
  __builtin_amdgcn_global_load_lds(
      (const __attribute__((address_space(1))) void*)g,
      (__attribute__((address_space(3))) void*)lds, 16, 0, 0);
}

__device__ __forceinline__ void store_out(float* p, float v) { *p = v; }
__device__ __forceinline__ void store_out(bf16* p, float v) { *p = __float2bfloat16(v); }

// ---------------------------------------------------------------------------
// Shared GEMM body (r5-proven 2-phase 128xBN structure).
// BIASMODE: 0 none, 1 col-bias, 2 row-bias,
//           3 exp(scale*acc) masked col<nv + partial row-sums to partp,
//           4 divide by sums (biasp, per-batch offset bz*1024).
// SWZ: 1 batched (id&7=batch), 2 chunked XCD swizzle over VGRID.
// VAR: 0 none, 1 skip M-tiles >= ceil128(nv), 2 skip N-tiles >= ceil128(nv),
//      3 K-iters = ceil32(nv).
template <typename OutT, int BIASMODE, int SWZ, int BN, int VAR, int NTX, int VGRID>
__device__ __forceinline__ void gemm_body(
    const bf16* __restrict__ Ag, const bf16* __restrict__ Bg,
    OutT* Cg, const float* __restrict__ biasp, const int* __restrict__ nvalid,
    float* __restrict__ partp, float scale, int K, int lda, int ldb, int ldc,
    long long sA, long long sB, long long sC, int id, bf16* As, bf16* Bs) {
  constexpr int NFR = BN / 32;
  constexpr int BCH = BN / 64;
  constexpr int ASZ = 128 * 32;   // one A buffer (elems)
  constexpr int BSZ = BN * 32;    // one B buffer (elems)

  int bz = 0, tile;
  if (SWZ == 1) { bz = id & 7; tile = id >> 3; }
  else { constexpr int q = VGRID >> 3; tile = (id & 7) * q + (id >> 3); }
  const int tn = tile % NTX, tm = tile / NTX;

  int nv = 0;
  if (VAR != 0 || BIASMODE == 3) nv = nvalid[bz];
  if (VAR == 1 && tm * 128 >= ((nv + 127) & ~127)) return;
  if (VAR == 2 && tn * BN >= ((nv + 127) & ~127)) return;
  const int nt = (VAR == 3) ? ((nv + 31) >> 5) : (K >> 5);

  const bf16* A = Ag + bz * sA;
  const bf16* BT = Bg + bz * sB;
  OutT* C = Cg + bz * sC;

  const int t = threadIdx.x;
  const int lane = t & 63;
  const int wid = t >> 6;
  const int wr = wid >> 1, wc = wid & 1;
  const int lo = lane & 15, hi = lane >> 4;

  const int arow0 = tm * 128, brow0 = tn * BN;

  const int idx0 = t, idx1 = 256 + t;
  const int r0 = idx0 >> 2, c0 = (idx0 & 3) * 8;
  const int r1 = idx1 >> 2, c1 = (idx1 & 3) * 8;
  const bf16* a0 = A + (long long)(arow0 + r0) * lda + c0;
  const bf16* a1 = A + (long long)(arow0 + r1) * lda + c1;
  const bf16* b0 = BT + (long long)(brow0 + r0) * ldb + c0;
  const bf16* b1 = BT + (long long)(brow0 + r1) * ldb + c1;

  f32x4 acc[4][NFR] = {};

  async_load16(a0, As + idx0 * 8);
  async_load16(a1, As + idx1 * 8);
  async_load16(b0, Bs + idx0 * 8);
  if (BCH == 2) async_load16(b1, Bs + idx1 * 8);
  __syncthreads();

  int cur = 0;
  for (int kt = 0; kt < nt; ++kt) {
    const int nxt = cur ^ 1;
    if (kt + 1 < nt) {
      const int k0 = (kt + 1) << 5;
      async_load16(a0 + k0, As + nxt * ASZ + idx0 * 8);
      async_load16(a1 + k0, As + nxt * ASZ + idx1 * 8);
      async_load16(b0 + k0, Bs + nxt * BSZ + idx0 * 8);
      if (BCH == 2) async_load16(b1 + k0, Bs + nxt * BSZ + idx1 * 8);
    }
    s16x8 a[4], b[NFR];
#pragma unroll
    for (int m = 0; m < 4; ++m)
      a[m] = *(const s16x8*)&As[cur * ASZ + (wr * 64 + m * 16 + lo) * 32 + hi * 8];
#pragma unroll
    for (int n = 0; n < NFR; ++n)
      b[n] = *(const s16x8*)&Bs[cur * BSZ + (wc * (BN / 2) + n * 16 + lo) * 32 + hi * 8];
#pragma unroll
    for (int m = 0; m < 4; ++m)
#pragma unroll
      for (int n = 0; n < NFR; ++n)
        acc[m][n] = __builtin_amdgcn_mfma_f32_16x16x32_bf16(a[m], b[n], acc[m][n], 0, 0, 0);
    __syncthreads();
    cur = nxt;
  }

  // ---- epilogue. C/D layout: col = lane&15, row = (lane>>4)*4 + reg
  float bcol[NFR];
#pragma unroll
  for (int n = 0; n < NFR; ++n) bcol[n] = 0.f;
  if (BIASMODE == 1) {
#pragma unroll
    for (int n = 0; n < NFR; ++n)
      bcol[n] = biasp[brow0 + wc * (BN / 2) + n * 16 + lo];
  }
  const float* srow = (BIASMODE == 4) ? (biasp + bz * 1024) : nullptr;
#pragma unroll
  for (int m = 0; m < 4; ++m) {
    const int row = arow0 + wr * 64 + m * 16 + hi * 4;
    float br[4] = {0.f, 0.f, 0.f, 0.f};
    if (BIASMODE == 2) {
      float4 t4 = *(const float4*)&biasp[row];
      br[0] = t4.x; br[1] = t4.y; br[2] = t4.z; br[3] = t4.w;
    }
    float inv[4] = {1.f, 1.f, 1.f, 1.f};
    if (BIASMODE == 4) {
      float4 s4 = *(const float4*)&srow[row];
      inv[0] = 1.f / s4.x; inv[1] = 1.f / s4.y; inv[2] = 1.f / s4.z; inv[3] = 1.f / s4.w;
    }
    float rs[4] = {0.f, 0.f, 0.f, 0.f};  // per-j partial row sums (BIASMODE 3)
#pragma unroll
    for (int n = 0; n < NFR; ++n) {
      const int col = brow0 + wc * (BN / 2) + n * 16 + lo;
#pragma unroll
      for (int j = 0; j < 4; ++j) {
        float v;
        if (BIASMODE == 3)      { v = (col < nv) ? __expf(acc[m][n][j] * scale) : 0.f; rs[j] += v; }
        else if (BIASMODE == 4) v = acc[m][n][j] * inv[j];
        else                    v = acc[m][n][j] * scale + bcol[n] + br[j];
        store_out(&C[(long long)(row + j) * ldc + col], v);
      }
    }
    if (BIASMODE == 3) {
      // reduce over lo (bits 0-3 of lane) -> 16-lane group sum; write one slot
#pragma unroll
      for (int j = 0; j < 4; ++j) {
        float s = rs[j];
        s += __shfl_xor(s, 1, 64);
        s += __shfl_xor(s, 2, 64);
        s += __shfl_xor(s, 4, 64);
        s += __shfl_xor(s, 8, 64);
        if (lo == 0)
          partp[(long long)(bz * 1024 + row + j) * 32 + tn * 2 + wc] = s;
      }
    }
  }
}

// standalone GEMM kernel wrapper
template <typename OutT, int BIASMODE, int SWZ, int BN, int VAR, int NTX, int VGRID>
__global__ void gemm_bt(const bf16* __restrict__ Ag, const bf16* __restrict__ Bg,
                        OutT* Cg, const float* __restrict__ biasp,
                        const int* __restrict__ nvalid, float* __restrict__ partp,
                        float scale, int K, int lda, int ldb, int ldc,
                        long long sA, long long sB, long long sC) {
  __shared__ bf16 As[2 * 128 * 32];
  __shared__ bf16 Bs[2 * BN * 32];
  gemm_body<OutT, BIASMODE, SWZ, BN, VAR, NTX, VGRID>(
      Ag, Bg, Cg, biasp, nvalid, partp, scale, K, lda, ldb, ldc,
      sA, sB, sC, blockIdx.x, As, Bs);
}

// ---------------------------------------------------------------------------
// fused Q / K' / V^T projections: block-range dispatch, 3072 blocks.
__global__ __launch_bounds__(256)
void proj3(const bf16* __restrict__ qb, const bf16* __restrict__ WqT,
           bf16* __restrict__ Qb, const float* __restrict__ bq,
           const bf16* __restrict__ kvc, const bf16* __restrict__ WkT,
           bf16* __restrict__ Kb, const float* __restrict__ bk,
           const bf16* __restrict__ WvT, bf16* __restrict__ VT,
           const float* __restrict__ bv, const int* __restrict__ nval) {
  __shared__ bf16 As[2 * 128 * 32];
  __shared__ bf16 Bs[2 * 128 * 32];
  const int id = blockIdx.x;
  if (id < 1024) {
    // Q projection: [8192,1024] @ WqT^T + bq, BN=64
    gemm_body<bf16, 1, 2, 64, 0, 16, 1024>(
        qb, WqT, Qb, bq, nullptr, nullptr, 1.f, 1024, 1024, 1024, 1024,
        0, 0, 0, id, As, Bs);
  } else if (id < 2048) {
    // K projection on compacted rows (skip dead M-tiles), BN=128
    gemm_body<bf16, 1, 1, 128, 1, 8, 1024>(
        kvc, WkT, Kb, bk, nval, nullptr, 1.f, 1024, 1024, 1024, 1024,
        2048ll * 1024, 0, 2048ll * 1024, id - 1024, As, Bs);
  } else {
    // V^T projection (skip dead N-tiles, row bias), BN=128
    gemm_body<bf16, 2, 1, 128, 2, 16, 1024>(
        WvT, kvc, VT, bv, nval, nullptr, 1.f, 1024, 1024, 1024, 2048,
        0, 2048ll * 1024, 1024ll * 2048, id - 2048, As, Bs);
  }
}

// ---------------------------------------------------------------------------
// stable compaction of unmasked key indices; one block per batch.
__global__ void compact_mask(const int* __restrict__ mask, int* __restrict__ cidx,
                             int* __restrict__ nvalid) {
  const int b = blockIdx.x;
  const int* m = mask + b * 2048;
  int* ci = cidx + b * 2048;
  const int t = threadIdx.x;
  __shared__ int cnt[256];
  __shared__ int base[256];
  int mv[8], c = 0;
#pragma unroll
  for (int j = 0; j < 8; ++j) { mv[j] = m[t * 8 + j]; c += (mv[j] != 0); }
  cnt[t] = c;
  __syncthreads();
  if (t == 0) {
    int s = 0;
    for (int i = 0; i < 256; ++i) { base[i] = s; s += cnt[i]; }
    nvalid[b] = s;
  }
  __syncthreads();
  int o = base[t];
#pragma unroll
  for (int j = 0; j < 8; ++j)
    if (mv[j]) ci[o++] = t * 8 + j;
}

// ---------------------------------------------------------------------------
// fused aux: [0,8192) cvt query; [8192,24576) gather-cvt kv; [24576,28672) W^T x4
__global__ __launch_bounds__(256)
void aux_prep(const float* __restrict__ query, bf16* __restrict__ qb,
              const float* __restrict__ kv, const int* __restrict__ cidx,
              const int* __restrict__ nvalid, bf16* __restrict__ kvc,
              const float* __restrict__ W0, const float* __restrict__ W1,
              const float* __restrict__ W2, const float* __restrict__ W3,
              bf16* __restrict__ O0, bf16* __restrict__ O1,
              bf16* __restrict__ O2, bf16* __restrict__ O3) {
  __shared__ float tile[32][33];
  const int id = blockIdx.x;
  const int t = threadIdx.x;
  if (id < 8192) {
    // query f32 -> bf16
    const long long i = (long long)id * 256 + t;
    float4 v = reinterpret_cast<const float4*>(query)[i];
    union { bf16 h[4]; unsigned long long u; } cv;
    cv.h[0] = __float2bfloat16(v.x);
    cv.h[1] = __float2bfloat16(v.y);
    cv.h[2] = __float2bfloat16(v.z);
    cv.h[3] = __float2bfloat16(v.w);
    reinterpret_cast<unsigned long long*>(qb)[i] = cv.u;
  } else if (id < 24576) {
    // gathered kv row f32 -> bf16 (pad rows duplicate last valid row)
    const int lid = id - 8192;
    const int b = lid >> 11, s = lid & 2047;
    const int nv = nvalid[b];
    if (s >= ((nv + 127) & ~127)) return;
    const int src = cidx[b * 2048 + min(s, nv - 1)];
    const float4 v = reinterpret_cast<const float4*>(
        kv + ((long long)b * 2048 + src) * 1024)[t];
    union { bf16 h[4]; unsigned long long u; } cv;
    cv.h[0] = __float2bfloat16(v.x);
    cv.h[1] = __float2bfloat16(v.y);
    cv.h[2] = __float2bfloat16(v.z);
    cv.h[3] = __float2bfloat16(v.w);
    reinterpret_cast<unsigned long long*>(
        kvc + ((long long)b * 2048 + s) * 1024)[t] = cv.u;
  } else {
    // 32x32 transpose tile of one of 4 weight matrices
    const int lid = id - 24576;
    const int z = lid >> 10, by = (lid >> 5) & 31, bx = lid & 31;
    const float* in; bf16* out;
    switch (z) {
      case 0: in = W0; out = O0; break;
      case 1: in = W1; out = O1; break;
      case 2: in = W2; out = O2; break;
      default: in = W3; out = O3; break;
    }
    const int tx = t & 31, ty = t >> 5;
#pragma unroll
    for (int i = 0; i < 32; i += 8)
      tile[ty + i][tx] = in[(long long)(by * 32 + ty + i) * 1024 + bx * 32 + tx];
    __syncthreads();
#pragma unroll
    for (int i = 0; i < 32; i += 8)
      out[(long long)(bx * 32 + ty + i) * 1024 + by * 32 + tx] =
          __float2bfloat16(tile[tx][ty + i]);
  }
}

// ---------------------------------------------------------------------------
// sums[row] = sum of partials over active tiles (deterministic fixed order)
__global__ void reduce_part(const float* __restrict__ part,
                            const int* __restrict__ nvalid,
                            float* __restrict__ sums) {
  const int row = blockIdx.x * 256 + threadIdx.x;  // 8192
  const int b = row >> 10;
  const int ntn = (((nvalid[b] + 127) & ~127) >> 7);
  float s = 0.f;
  for (int i = 0; i < ntn * 2; ++i) s += part[(long long)row * 32 + i];
  sums[row] = s;
}

// ---------------------------------------------------------------------------
extern "C" void kernel_launch(void* const* d_in, const int* in_sizes, int n_in,
                              void* d_out, int out_size, void* d_ws, size_t ws_size,
                              hipStream_t stream) {
  const float* query = (const float*)d_in[0];      // [8,1024,1024]
  const float* key_value = (const float*)d_in[1];  // [8,2048,1024]
  const int* key_mask = (const int*)d_in[2];       // [8,2048]
  const float* Wq = (const float*)d_in[3];
  const float* bq = (const float*)d_in[4];
  const float* Wk = (const float*)d_in[5];
  const float* bk = (const float*)d_in[6];
  const float* Wv = (const float*)d_in[7];
  const float* bv = (const float*)d_in[8];
  const float* Wo = (const float*)d_in[9];
  const float* bo = (const float*)d_in[10];
  float* out = (float*)d_out;

  char* ws = (char*)d_ws;
  size_t off = 0;
  auto alloc = [&](size_t bytes) {
    char* p = ws + off;
    off += (bytes + 255) & ~(size_t)255;
    return p;
  };
  bf16* qb   = (bf16*)alloc(8192ull * 1024 * 2);
  bf16* kvc  = (bf16*)alloc(16384ull * 1024 * 2);
  bf16* WqT  = (bf16*)alloc(1024ull * 1024 * 2);
  bf16* WkT  = (bf16*)alloc(1024ull * 1024 * 2);
  bf16* WvT  = (bf16*)alloc(1024ull * 1024 * 2);
  bf16* WoT  = (bf16*)alloc(1024ull * 1024 * 2);
  bf16* Qb   = (bf16*)alloc(8192ull * 1024 * 2);
  bf16* Kb   = (bf16*)alloc(16384ull * 1024 * 2);
  bf16* VT   = (bf16*)alloc(8192ull * 2048 * 2);
  bf16* P    = (bf16*)alloc(8ull * 1024 * 2048 * 2);
  int*  cidx = (int*)alloc(8 * 2048 * 4);
  int*  nval = (int*)alloc(8 * 4);
  float* part = (float*)alloc(8192ull * 32 * 4);
  float* sums = (float*)alloc(8192 * 4);
  bf16* Cb = Qb;  // alias: Qb dead after scores GEMM

  // 1. compaction, then fused conversions/gather/weight-transpose
  compact_mask<<<8, 256, 0, stream>>>(key_mask, cidx, nval);
  aux_prep<<<28672, 256, 0, stream>>>(query, qb, key_value, cidx, nval, kvc,
                                      Wq, Wk, Wv, Wo, WqT, WkT, WvT, WoT);

  // 2. fused Q / K' / V^T projections
  proj3<<<3072, 256, 0, stream>>>(qb, WqT, Qb, bq, kvc, WkT, Kb, bk,
                                  WvT, VT, bv, nval);

  // 3. scores: P~ = exp((Q @ K'^T)/32) (0 beyond nv) + partial row sums
  gemm_bt<bf16, 3, 1, 128, 2, 16, 1024><<<1024, 256, 0, stream>>>(
      Qb, Kb, P, nullptr, nval, part, 0.03125f, 1024, 1024, 1024, 2048,
      1024ll * 1024, 2048ll * 1024, 1024ll * 2048);

  // 4. reduce partials -> row sums
  reduce_part<<<32, 256, 0, stream>>>(part, nval, sums);

  // 5. context = (P~ @ V') / rowsum  (var-K)
  gemm_bt<bf16, 4, 1, 64, 3, 16, 1024><<<1024, 256, 0, stream>>>(
      P, VT, Cb, sums, nval, nullptr, 1.f, 2048, 2048, 2048, 1024,
      1024ll * 2048, 1024ll * 2048, 1024ll * 1024);

  // 6. out = Cb @ Wo + bo (f32)
  gemm_bt<float, 1, 2, 64, 0, 16, 1024><<<1024, 256, 0, stream>>>(
      Cb, WoT, out, bo, nullptr, nullptr, 1.f, 1024, 1024, 1024, 1024,
      0, 0, 0);
}

// Round 11
// 217.947 us; speedup vs baseline: 1.0303x; 1.0303x over previous
//
#include <hip/hip_runtime.h>
#include <hip/hip_bf16.h>

typedef __hip_bfloat16 bf16;
typedef float f32x4 __attribute__((ext_vector_type(4)));
typedef short s16x8 __attribute__((ext_vector_type(8)));

// ---------------------------------------------------------------------------
__device__ __forceinline__ void async_load16(const void* g, void* lds) {
  __builtin_amdgcn_global_load_lds(
      (const __attribute__((address_space(1))) void*)g,
      (__attribute__((address_space(3))) void*)lds, 16, 0, 0);
}

__device__ __forceinline__ void store_out(float* p, float v) { *p = v; }
__device__ __forceinline__ void store_out(bf16* p, float v) { *p = __float2bfloat16(v); }

// ---------------------------------------------------------------------------
// r5-proven 2-phase 128xBN GEMM.
// BIASMODE: 0 none, 1 col-bias, 2 row-bias,
//           3 exp(scale*acc) masked col<nv + partial row-sums to partp,
//           4 divide by sums (biasp, per-batch offset bz*1024).
// SWZ: 1 batched (id&7=batch), 2 chunked XCD swizzle over grid.
// VAR: 0 none, 1 skip M-tiles >= ceil128(nv), 2 skip N-tiles >= ceil128(nv),
//      3 K-iters = ceil32(nv).
template <typename OutT, int BIASMODE, int SWZ, int BN, int VAR, int NTX>
__global__ void gemm_bt(const bf16* __restrict__ Ag, const bf16* __restrict__ Bg,
                        OutT* Cg, const float* __restrict__ biasp,
                        const int* __restrict__ nvalid, float* __restrict__ partp,
                        float scale, int K, int lda, int ldb, int ldc,
                        long long sA, long long sB, long long sC) {
  constexpr int NFR = BN / 32;
  constexpr int BCH = BN / 64;
  __shared__ bf16 As[2][128 * 32];
  __shared__ bf16 Bs[2][BN * 32];

  const int id = blockIdx.x;
  int bz = 0, tile;
  if (SWZ == 1) { bz = id & 7; tile = id >> 3; }
  else { const int q = gridDim.x >> 3; tile = (id & 7) * q + (id >> 3); }
  const int tn = tile % NTX, tm = tile / NTX;

  int nv = 0;
  if (VAR != 0 || BIASMODE == 3) nv = nvalid[bz];
  if (VAR == 1 && tm * 128 >= ((nv + 127) & ~127)) return;
  if (VAR == 2 && tn * BN >= ((nv + 127) & ~127)) return;
  const int nt = (VAR == 3) ? ((nv + 31) >> 5) : (K >> 5);

  const bf16* A = Ag + bz * sA;
  const bf16* BT = Bg + bz * sB;
  OutT* C = Cg + bz * sC;

  const int t = threadIdx.x;
  const int lane = t & 63;
  const int wid = t >> 6;
  const int wr = wid >> 1, wc = wid & 1;
  const int lo = lane & 15, hi = lane >> 4;

  const int arow0 = tm * 128, brow0 = tn * BN;

  const int idx0 = t, idx1 = 256 + t;
  const int r0 = idx0 >> 2, c0 = (idx0 & 3) * 8;
  const int r1 = idx1 >> 2, c1 = (idx1 & 3) * 8;
  const bf16* a0 = A + (long long)(arow0 + r0) * lda + c0;
  const bf16* a1 = A + (long long)(arow0 + r1) * lda + c1;
  const bf16* b0 = BT + (long long)(brow0 + r0) * ldb + c0;
  const bf16* b1 = BT + (long long)(brow0 + r1) * ldb + c1;

  f32x4 acc[4][NFR] = {};

  async_load16(a0, &As[0][idx0 * 8]);
  async_load16(a1, &As[0][idx1 * 8]);
  async_load16(b0, &Bs[0][idx0 * 8]);
  if (BCH == 2) async_load16(b1, &Bs[0][idx1 * 8]);
  __syncthreads();

  int cur = 0;
  for (int kt = 0; kt < nt; ++kt) {
    const int nxt = cur ^ 1;
    if (kt + 1 < nt) {
      const int k0 = (kt + 1) << 5;
      async_load16(a0 + k0, &As[nxt][idx0 * 8]);
      async_load16(a1 + k0, &As[nxt][idx1 * 8]);
      async_load16(b0 + k0, &Bs[nxt][idx0 * 8]);
      if (BCH == 2) async_load16(b1 + k0, &Bs[nxt][idx1 * 8]);
    }
    s16x8 a[4], b[NFR];
#pragma unroll
    for (int m = 0; m < 4; ++m)
      a[m] = *(const s16x8*)&As[cur][(wr * 64 + m * 16 + lo) * 32 + hi * 8];
#pragma unroll
    for (int n = 0; n < NFR; ++n)
      b[n] = *(const s16x8*)&Bs[cur][(wc * (BN / 2) + n * 16 + lo) * 32 + hi * 8];
#pragma unroll
    for (int m = 0; m < 4; ++m)
#pragma unroll
      for (int n = 0; n < NFR; ++n)
        acc[m][n] = __builtin_amdgcn_mfma_f32_16x16x32_bf16(a[m], b[n], acc[m][n], 0, 0, 0);
    __syncthreads();
    cur = nxt;
  }

  // ---- epilogue. C/D layout: col = lane&15, row = (lane>>4)*4 + reg
  float bcol[NFR];
#pragma unroll
  for (int n = 0; n < NFR; ++n) bcol[n] = 0.f;
  if (BIASMODE == 1) {
#pragma unroll
    for (int n = 0; n < NFR; ++n)
      bcol[n] = biasp[brow0 + wc * (BN / 2) + n * 16 + lo];
  }
  const float* srow = (BIASMODE == 4) ? (biasp + bz * 1024) : nullptr;
#pragma unroll
  for (int m = 0; m < 4; ++m) {
    const int row = arow0 + wr * 64 + m * 16 + hi * 4;
    float br[4] = {0.f, 0.f, 0.f, 0.f};
    if (BIASMODE == 2) {
      float4 t4 = *(const float4*)&biasp[row];
      br[0] = t4.x; br[1] = t4.y; br[2] = t4.z; br[3] = t4.w;
    }
    float inv[4] = {1.f, 1.f, 1.f, 1.f};
    if (BIASMODE == 4) {
      float4 s4 = *(const float4*)&srow[row];
      inv[0] = 1.f / s4.x; inv[1] = 1.f / s4.y; inv[2] = 1.f / s4.z; inv[3] = 1.f / s4.w;
    }
    float rs[4] = {0.f, 0.f, 0.f, 0.f};  // partial row sums (BIASMODE 3)
#pragma unroll
    for (int n = 0; n < NFR; ++n) {
      const int col = brow0 + wc * (BN / 2) + n * 16 + lo;
#pragma unroll
      for (int j = 0; j < 4; ++j) {
        float v;
        if (BIASMODE == 3)      { v = (col < nv) ? __expf(acc[m][n][j] * scale) : 0.f; rs[j] += v; }
        else if (BIASMODE == 4) v = acc[m][n][j] * inv[j];
        else                    v = acc[m][n][j] * scale + bcol[n] + br[j];
        store_out(&C[(long long)(row + j) * ldc + col], v);
      }
    }
    if (BIASMODE == 3) {
      // reduce over lo (lane bits 0-3) -> 16-lane group sum; one slot per tile
#pragma unroll
      for (int j = 0; j < 4; ++j) {
        float s = rs[j];
        s += __shfl_xor(s, 1, 64);
        s += __shfl_xor(s, 2, 64);
        s += __shfl_xor(s, 4, 64);
        s += __shfl_xor(s, 8, 64);
        if (lo == 0)
          partp[(long long)(bz * 1024 + row + j) * 32 + tn * 2 + wc] = s;
      }
    }
  }
}

// ---------------------------------------------------------------------------
// stable compaction of unmasked key indices; one block per batch.
__global__ void compact_mask(const int* __restrict__ mask, int* __restrict__ cidx,
                             int* __restrict__ nvalid) {
  const int b = blockIdx.x;
  const int* m = mask + b * 2048;
  int* ci = cidx + b * 2048;
  const int t = threadIdx.x;
  __shared__ int cnt[256];
  __shared__ int base[256];
  int mv[8], c = 0;
#pragma unroll
  for (int j = 0; j < 8; ++j) { mv[j] = m[t * 8 + j]; c += (mv[j] != 0); }
  cnt[t] = c;
  __syncthreads();
  if (t == 0) {
    int s = 0;
    for (int i = 0; i < 256; ++i) { base[i] = s; s += cnt[i]; }
    nvalid[b] = s;
  }
  __syncthreads();
  int o = base[t];
#pragma unroll
  for (int j = 0; j < 8; ++j)
    if (mv[j]) ci[o++] = t * 8 + j;
}

// ---------------------------------------------------------------------------
// fused aux: [0,8192) cvt query; [8192,24576) gather-cvt kv; [24576,28672) W^T x4
__global__ __launch_bounds__(256)
void aux_prep(const float* __restrict__ query, bf16* __restrict__ qb,
              const float* __restrict__ kv, const int* __restrict__ cidx,
              const int* __restrict__ nvalid, bf16* __restrict__ kvc,
              const float* __restrict__ W0, const float* __restrict__ W1,
              const float* __restrict__ W2, const float* __restrict__ W3,
              bf16* __restrict__ O0, bf16* __restrict__ O1,
              bf16* __restrict__ O2, bf16* __restrict__ O3) {
  __shared__ float tile[32][33];
  const int id = blockIdx.x;
  const int t = threadIdx.x;
  if (id < 8192) {
    const long long i = (long long)id * 256 + t;
    float4 v = reinterpret_cast<const float4*>(query)[i];
    union { bf16 h[4]; unsigned long long u; } cv;
    cv.h[0] = __float2bfloat16(v.x);
    cv.h[1] = __float2bfloat16(v.y);
    cv.h[2] = __float2bfloat16(v.z);
    cv.h[3] = __float2bfloat16(v.w);
    reinterpret_cast<unsigned long long*>(qb)[i] = cv.u;
  } else if (id < 24576) {
    const int lid = id - 8192;
    const int b = lid >> 11, s = lid & 2047;
    const int nv = nvalid[b];
    if (s >= ((nv + 127) & ~127)) return;
    const int src = cidx[b * 2048 + min(s, nv - 1)];
    const float4 v = reinterpret_cast<const float4*>(
        kv + ((long long)b * 2048 + src) * 1024)[t];
    union { bf16 h[4]; unsigned long long u; } cv;
    cv.h[0] = __float2bfloat16(v.x);
    cv.h[1] = __float2bfloat16(v.y);
    cv.h[2] = __float2bfloat16(v.z);
    cv.h[3] = __float2bfloat16(v.w);
    reinterpret_cast<unsigned long long*>(
        kvc + ((long long)b * 2048 + s) * 1024)[t] = cv.u;
  } else {
    const int lid = id - 24576;
    const int z = lid >> 10, by = (lid >> 5) & 31, bx = lid & 31;
    const float* in; bf16* out;
    switch (z) {
      case 0: in = W0; out = O0; break;
      case 1: in = W1; out = O1; break;
      case 2: in = W2; out = O2; break;
      default: in = W3; out = O3; break;
    }
    const int tx = t & 31, ty = t >> 5;
#pragma unroll
    for (int i = 0; i < 32; i += 8)
      tile[ty + i][tx] = in[(long long)(by * 32 + ty + i) * 1024 + bx * 32 + tx];
    __syncthreads();
#pragma unroll
    for (int i = 0; i < 32; i += 8)
      out[(long long)(bx * 32 + ty + i) * 1024 + by * 32 + tx] =
          __float2bfloat16(tile[tx][ty + i]);
  }
}

// ---------------------------------------------------------------------------
// sums[row] = sum of partials over active tiles (deterministic fixed order)
__global__ void reduce_part(const float* __restrict__ part,
                            const int* __restrict__ nvalid,
                            float* __restrict__ sums) {
  const int row = blockIdx.x * 256 + threadIdx.x;  // 8192
  const int b = row >> 10;
  const int ntn = (((nvalid[b] + 127) & ~127) >> 7);
  float s = 0.f;
  for (int i = 0; i < ntn * 2; ++i) s += part[(long long)row * 32 + i];
  sums[row] = s;
}

// ---------------------------------------------------------------------------
extern "C" void kernel_launch(void* const* d_in, const int* in_sizes, int n_in,
                              void* d_out, int out_size, void* d_ws, size_t ws_size,
                              hipStream_t stream) {
  const float* query = (const float*)d_in[0];      // [8,1024,1024]
  const float* key_value = (const float*)d_in[1];  // [8,2048,1024]
  const int* key_mask = (const int*)d_in[2];       // [8,2048]
  const float* Wq = (const float*)d_in[3];
  const float* bq = (const float*)d_in[4];
  const float* Wk = (const float*)d_in[5];
  const float* bk = (const float*)d_in[6];
  const float* Wv = (const float*)d_in[7];
  const float* bv = (const float*)d_in[8];
  const float* Wo = (const float*)d_in[9];
  const float* bo = (const float*)d_in[10];
  float* out = (float*)d_out;

  char* ws = (char*)d_ws;
  size_t off = 0;
  auto alloc = [&](size_t bytes) {
    char* p = ws + off;
    off += (bytes + 255) & ~(size_t)255;
    return p;
  };
  bf16* qb   = (bf16*)alloc(8192ull * 1024 * 2);
  bf16* kvc  = (bf16*)alloc(16384ull * 1024 * 2);
  bf16* WqT  = (bf16*)alloc(1024ull * 1024 * 2);
  bf16* WkT  = (bf16*)alloc(1024ull * 1024 * 2);
  bf16* WvT  = (bf16*)alloc(1024ull * 1024 * 2);
  bf16* WoT  = (bf16*)alloc(1024ull * 1024 * 2);
  bf16* Qb   = (bf16*)alloc(8192ull * 1024 * 2);
  bf16* Kb   = (bf16*)alloc(16384ull * 1024 * 2);
  bf16* VT   = (bf16*)alloc(8192ull * 2048 * 2);
  bf16* P    = (bf16*)alloc(8ull * 1024 * 2048 * 2);
  int*  cidx = (int*)alloc(8 * 2048 * 4);
  int*  nval = (int*)alloc(8 * 4);
  float* part = (float*)alloc(8192ull * 32 * 4);
  float* sums = (float*)alloc(8192 * 4);
  bf16* Cb = Qb;  // alias: Qb dead after scores GEMM

  // 1. compaction, then fused conversions/gather/weight-transpose
  compact_mask<<<8, 256, 0, stream>>>(key_mask, cidx, nval);
  aux_prep<<<28672, 256, 0, stream>>>(query, qb, key_value, cidx, nval, kvc,
                                      Wq, Wk, Wv, Wo, WqT, WkT, WvT, WoT);

  // 2. Q projection (separate instantiation, clean codegen)
  gemm_bt<bf16, 1, 2, 64, 0, 16><<<1024, 256, 0, stream>>>(
      qb, WqT, Qb, bq, nullptr, nullptr, 1.f, 1024, 1024, 1024, 1024, 0, 0, 0);

  // 3. K projection (compacted rows, skip dead M-tiles)
  gemm_bt<bf16, 1, 1, 128, 1, 8><<<1024, 256, 0, stream>>>(
      kvc, WkT, Kb, bk, nval, nullptr, 1.f, 1024, 1024, 1024, 1024,
      2048ll * 1024, 0, 2048ll * 1024);

  // 4. V^T projection (skip dead N-tiles, row bias)
  gemm_bt<bf16, 2, 1, 128, 2, 16><<<1024, 256, 0, stream>>>(
      WvT, kvc, VT, bv, nval, nullptr, 1.f, 1024, 1024, 1024, 2048,
      0, 2048ll * 1024, 1024ll * 2048);

  // 5. scores: P~ = exp((Q @ K'^T)/32) (0 beyond nv) + partial row sums
  gemm_bt<bf16, 3, 1, 128, 2, 16><<<1024, 256, 0, stream>>>(
      Qb, Kb, P, nullptr, nval, part, 0.03125f, 1024, 1024, 1024, 2048,
      1024ll * 1024, 2048ll * 1024, 1024ll * 2048);

  // 6. reduce partials -> row sums
  reduce_part<<<32, 256, 0, stream>>>(part, nval, sums);

  // 7. context = (P~ @ V') / rowsum  (var-K)
  gemm_bt<bf16, 4, 1, 64, 3, 16><<<1024, 256, 0, stream>>>(
      P, VT, Cb, sums, nval, nullptr, 1.f, 2048, 2048, 2048, 1024,
      1024ll * 2048, 1024ll * 2048, 1024ll * 1024);

  // 8. out = Cb @ Wo + bo (f32)
  gemm_bt<float, 1, 2, 64, 0, 16><<<1024, 256, 0, stream>>>(
      Cb, WoT, out, bo, nullptr, nullptr, 1.f, 1024, 1024, 1024, 1024, 0, 0, 0);
}